// Round 1
// baseline (525.565 us; speedup 1.0000x reference)
//
#include <hip/hip_runtime.h>
#include <math.h>

typedef float f4 __attribute__((ext_vector_type(4)));

#define B_    16
#define TMAX  4096
#define DM    1024
#define H_    16
#define DH    64
#define SPLIT 8
#define SCALE 0.125f
#define ROPE_L 0.28782313662425572f   // ln(10000)/32

// ws layout (float offsets)
#define WS_PO    16384             // B*H*SPLIT*64 = 131072
#define WS_PM    147456            // 2048
#define WS_PL    149504            // 2048
#define WS_OF    151552            // 16384
#define WS_BIG   167936            // 393216 qkv partials

__device__ __forceinline__ f4 ldnt(const f4* p) { return __builtin_nontemporal_load(p); }

__device__ __forceinline__ float wred_max(float v) {
#pragma unroll
    for (int o = 32; o > 0; o >>= 1) v = fmaxf(v, __shfl_xor(v, o, 64));
    return v;
}
__device__ __forceinline__ float wred_sum(float v) {
#pragma unroll
    for (int o = 32; o > 0; o >>= 1) v += __shfl_xor(v, o, 64);
    return v;
}

// grid (8 echunks, 16 heads, 3 matrices), block 256 = 64 d x 4 e-subgroups
__global__ __launch_bounds__(256) void k_qkv(const float* __restrict__ x,
                      const float* __restrict__ Wq, const float* __restrict__ Wk,
                      const float* __restrict__ Wv, float* __restrict__ ws) {
    const int ec = blockIdx.x, h = blockIdx.y, mat = blockIdx.z;
    const float* W = (mat == 0) ? Wq : ((mat == 1) ? Wk : Wv);
    const int tid = threadIdx.x;
    const int d = tid & 63, es = tid >> 6;
    __shared__ float xs[B_][128];
    __shared__ float red[4][B_][64];
    for (int i = tid; i < B_ * 128; i += 256) {
        int b = i >> 7, e = i & 127;
        xs[b][e] = x[b * DM + ec * 128 + e];
    }
    __syncthreads();
    float acc[B_];
#pragma unroll
    for (int b = 0; b < B_; b++) acc[b] = 0.f;
    for (int i = 0; i < 32; i++) {
        int el = es * 32 + i;
        int e = ec * 128 + el;
        float w = W[((size_t)e * H_ + h) * DH + d];
#pragma unroll
        for (int b = 0; b < B_; b++) acc[b] += xs[b][el] * w;
    }
#pragma unroll
    for (int b = 0; b < B_; b++) red[es][b][d] = acc[b];
    __syncthreads();
    const int b4 = tid >> 6;
#pragma unroll
    for (int bb = 0; bb < 4; bb++) {
        int b = b4 * 4 + bb;
        float v = red[0][b][d] + red[1][b][d] + red[2][b][d] + red[3][b][d];
        ws[WS_BIG + (((size_t)(mat * 8 + ec) * B_ + b) * H_ + h) * DH + d] = v;
    }
}

// grid (SPLIT, H, B) = 2048 blocks, block 256
// NOTE: does NOT read/write the cache at slot P -- the fresh k/v row is
// reduced from the qkv partials into LDS (no input mutation anywhere).
__global__ __launch_bounds__(256) void k_attn(const float* __restrict__ K,
                                              const float* __restrict__ V,
                                              const float* __restrict__ bq,
                                              const float* __restrict__ bk,
                                              const float* __restrict__ bv,
                                              const int* __restrict__ cidx,
                                              float* __restrict__ ws) {
    const int s = blockIdx.x, h = blockIdx.y, b = blockIdx.z;
    const int tid = threadIdx.x;
    const int P = *cidx;
    const int n = P + 1;
    const int chunk = (n + SPLIT - 1) / SPLIT;
    const int t0 = s * chunk;
    int t1 = t0 + chunk; if (t1 > n) t1 = n;
    const int len = (t1 > t0) ? (t1 - t0) : 0;
    const int bh = b * H_ + h;
    const bool hasP = (P >= t0) && (P < t1);

    __shared__ float qr[64];
    __shared__ float kPs[64];
    __shared__ float vPs[64];
    __shared__ float sc[512];
    __shared__ float rb_m[4], rb_s[4];
    __shared__ float ov[16][64];

    if (tid < 64) {
        const int d = tid;
        const float* big = ws + WS_BIG;
        const size_t matstride = (size_t)8 * B_ * H_ * DH;
        // reduce q partials in-block (2 KB of reads)
        float q = bq[h * 64 + d];
#pragma unroll
        for (int ec = 0; ec < 8; ec++)
            q += big[(((size_t)ec * B_ + b) * H_ + h) * DH + d];
        int j = (d < 32) ? d : (d - 32);
        float invf = __expf(-(float)j * ROPE_L);
        float sn, c;
        sincosf((float)P * invf, &sn, &c);
        float qp = __shfl_xor(q, 32, 64);
        qr[d] = (d < 32) ? (q * c - qp * sn) : (qp * sn + q * c);
        if (hasP) {
            float kk = bk[h * 64 + d], vv = bv[h * 64 + d];
#pragma unroll
            for (int ec = 0; ec < 8; ec++) {
                size_t base = (((size_t)ec * B_ + b) * H_ + h) * DH + d;
                kk += big[matstride + base];
                vv += big[2 * matstride + base];
            }
            kPs[d] = kk;   // un-rotated; phase A ropes all K rows uniformly
            vPs[d] = vv;
        }
    }
    __syncthreads();

    // Phase A: 8 lanes per position, fully-coalesced K rows
    const int pos_sub = tid >> 3, q = tid & 7;
    float qa0 = qr[4 * q + 0], qa1 = qr[4 * q + 1], qa2 = qr[4 * q + 2], qa3 = qr[4 * q + 3];
    float qb0 = qr[4 * q + 32], qb1 = qr[4 * q + 33], qb2 = qr[4 * q + 34], qb3 = qr[4 * q + 35];
    float if0 = __expf(-(float)(4 * q + 0) * ROPE_L);
    float if1 = __expf(-(float)(4 * q + 1) * ROPE_L);
    float if2 = __expf(-(float)(4 * q + 2) * ROPE_L);
    float if3 = __expf(-(float)(4 * q + 3) * ROPE_L);

    float tmax = -3.0e38f;
    for (int base = 0; base < len; base += 32) {
        int idx = base + pos_sub;
        bool act = idx < len;
        int t = t0 + idx;
        f4 k1 = {0.f, 0.f, 0.f, 0.f}, k2 = {0.f, 0.f, 0.f, 0.f};
        if (act) {
            if (t == P) {
                const f4* kp = (const f4*)kPs;
                k1 = kp[q];
                k2 = kp[q + 8];
            } else {
                const f4* kp = (const f4*)(K + (((size_t)b * TMAX + t) * H_ + h) * DH);
                k1 = ldnt(kp + q);
                k2 = ldnt(kp + q + 8);
            }
        }
        float tf = (float)t;
        float s0, c0, s1, c1, s2, c2, s3, c3;
        sincosf(tf * if0, &s0, &c0);
        sincosf(tf * if1, &s1, &c1);
        sincosf(tf * if2, &s2, &c2);
        sincosf(tf * if3, &s3, &c3);
        float p = k1.x * (qa0 * c0 + qb0 * s0) + k2.x * (qb0 * c0 - qa0 * s0)
                + k1.y * (qa1 * c1 + qb1 * s1) + k2.y * (qb1 * c1 - qa1 * s1)
                + k1.z * (qa2 * c2 + qb2 * s2) + k2.z * (qb2 * c2 - qa2 * s2)
                + k1.w * (qa3 * c3 + qb3 * s3) + k2.w * (qb3 * c3 - qa3 * s3);
#pragma unroll
        for (int o = 1; o < 8; o <<= 1) p += __shfl_xor(p, o, 64);
        if (act) {
            float sv = p * SCALE;
            if (q == 0) sc[idx] = sv;
            tmax = fmaxf(tmax, sv);
        }
    }
    float wm = wred_max(tmax);
    if ((tid & 63) == 0) rb_m[tid >> 6] = wm;
    __syncthreads();
    float m = fmaxf(fmaxf(rb_m[0], rb_m[1]), fmaxf(rb_m[2], rb_m[3]));

    float tsum = 0.f;
    for (int idx = tid; idx < len; idx += 256) {
        float pp = __expf(sc[idx] - m);
        sc[idx] = pp;
        tsum += pp;
    }
    float wsum = wred_sum(tsum);
    if ((tid & 63) == 0) rb_s[tid >> 6] = wsum;
    __syncthreads();
    float l = rb_s[0] + rb_s[1] + rb_s[2] + rb_s[3];

    // Phase B: float4 over d, 16 position-groups, coalesced rows
    const int d4 = tid & 15, grp = tid >> 4;
    f4 acc4 = {0.f, 0.f, 0.f, 0.f};
#pragma unroll 4
    for (int idx = grp; idx < len; idx += 16) {
        int t = t0 + idx;
        f4 vv;
        if (t == P) {
            vv = ((const f4*)vPs)[d4];
        } else {
            vv = ldnt((const f4*)(V + (((size_t)b * TMAX + t) * H_ + h) * DH) + d4);
        }
        acc4 += sc[idx] * vv;
    }
    *(f4*)&ov[grp][d4 * 4] = acc4;
    __syncthreads();
    if (tid < 64) {
        float o = 0.f;
#pragma unroll
        for (int g = 0; g < 16; g++) o += ov[g][tid];
        ws[WS_PO + ((size_t)bh * SPLIT + s) * 64 + tid] = o;
        if (tid == 0) {
            ws[WS_PM + bh * SPLIT + s] = (len > 0) ? m : -1.0e30f;
            ws[WS_PL + bh * SPLIT + s] = l;
        }
    }
}

// 256 blocks x 64 threads
__global__ void k_combine(float* __restrict__ ws) {
    int bh = blockIdx.x;
    int d = threadIdx.x;
    const float* pm = ws + WS_PM + bh * SPLIT;
    const float* pl = ws + WS_PL + bh * SPLIT;
    const float* po = ws + WS_PO + (size_t)bh * SPLIT * 64;
    float m = -3.0e38f;
#pragma unroll
    for (int s = 0; s < SPLIT; s++) m = fmaxf(m, pm[s]);
    float l = 0.f, o = 0.f;
#pragma unroll
    for (int s = 0; s < SPLIT; s++) {
        float w = __expf(pm[s] - m);
        l += pl[s] * w;
        o += po[s * 64 + d] * w;
    }
    ws[WS_OF + bh * 64 + d] = o / l;
}

// fused output projection + bias: grid 16 (e-chunks), block 256.
// Each block accumulates over ALL 1024 hd dims and writes out directly.
__global__ __launch_bounds__(256) void k_oproj(const float* __restrict__ Wo,
                                               const float* __restrict__ bo,
                                               const float* __restrict__ ws,
                                               float* __restrict__ out) {
    const int ec = blockIdx.x;
    const int tid = threadIdx.x;
    const int el = tid & 63, grp = tid >> 6;
    const int e = ec * 64 + el;
    __shared__ float ofs[B_][64];
    __shared__ float red[4][B_][64];
    float acc[B_];
#pragma unroll
    for (int b = 0; b < B_; b++) acc[b] = 0.f;
    for (int hc = 0; hc < 16; hc++) {
        for (int i = tid; i < B_ * 64; i += 256) {
            int b = i >> 6, j = i & 63;
            ofs[b][j] = ws[WS_OF + b * (H_ * DH) + hc * 64 + j];
        }
        __syncthreads();
        for (int i = 0; i < 16; i++) {
            int hl = grp * 16 + i;
            float w = Wo[(size_t)(hc * 64 + hl) * DM + e];
#pragma unroll
            for (int b = 0; b < B_; b++) acc[b] += ofs[b][hl] * w;
        }
        __syncthreads();
    }
#pragma unroll
    for (int b = 0; b < B_; b++) red[grp][b][el] = acc[b];
    __syncthreads();
    const int b4 = tid >> 6;
    float bias = bo[e];
#pragma unroll
    for (int bb = 0; bb < 4; bb++) {
        int b = b4 * 4 + bb;
        float v = red[0][b][el] + red[1][b][el] + red[2][b][el] + red[3][b][el];
        out[(size_t)b * DM + e] = bias + v;
    }
}

extern "C" void kernel_launch(void* const* d_in, const int* in_sizes, int n_in,
                              void* d_out, int out_size, void* d_ws, size_t ws_size,
                              hipStream_t stream) {
    const float* x  = (const float*)d_in[0];
    const float* ck = (const float*)d_in[1];
    const float* cv = (const float*)d_in[2];
    const float* Wq = (const float*)d_in[3];
    const float* bq = (const float*)d_in[4];
    const float* Wk = (const float*)d_in[5];
    const float* bk = (const float*)d_in[6];
    const float* Wv = (const float*)d_in[7];
    const float* bv = (const float*)d_in[8];
    const float* Wo = (const float*)d_in[9];
    const float* bo = (const float*)d_in[10];
    const int* cidx = (const int*)d_in[11];
    float* ws  = (float*)d_ws;
    float* out = (float*)d_out;

    k_qkv<<<dim3(8, H_, 3), 256, 0, stream>>>(x, Wq, Wk, Wv, ws);
    k_attn<<<dim3(SPLIT, H_, B_), 256, 0, stream>>>(ck, cv, bq, bk, bv, cidx, ws);
    k_combine<<<B_ * H_, 64, 0, stream>>>(ws);
    k_oproj<<<dim3(16), 256, 0, stream>>>(Wo, bo, ws, out);
}

// Round 2
// 479.555 us; speedup vs baseline: 1.0959x; 1.0959x over previous
//
#include <hip/hip_runtime.h>
#include <math.h>

typedef float f4 __attribute__((ext_vector_type(4)));

#define B_    16
#define TMAX  4096
#define DM    1024
#define H_    16
#define DH    64
#define SPLIT 8
#define SCALE 0.125f
#define ROPE_L 0.28782313662425572f   // ln(10000)/32

// ws layout (float offsets)
#define WS_Q     0                 // 16384
#define WS_PO    16384             // B*H*SPLIT*64 = 131072
#define WS_PM    147456            // 2048
#define WS_PL    149504            // 2048
#define WS_OF    151552            // 16384
#define WS_BIG   167936            // 393216 qkv partials

__device__ __forceinline__ f4 ldnt(const f4* p) { return __builtin_nontemporal_load(p); }

__device__ __forceinline__ float wred_max(float v) {
#pragma unroll
    for (int o = 32; o > 0; o >>= 1) v = fmaxf(v, __shfl_xor(v, o, 64));
    return v;
}
__device__ __forceinline__ float wred_sum(float v) {
#pragma unroll
    for (int o = 32; o > 0; o >>= 1) v += __shfl_xor(v, o, 64);
    return v;
}

// grid (8 echunks, 16 heads, 3 matrices), block 256 = 64 d x 4 e-subgroups
__global__ __launch_bounds__(256) void k_qkv(const float* __restrict__ x,
                      const float* __restrict__ Wq, const float* __restrict__ Wk,
                      const float* __restrict__ Wv, float* __restrict__ ws) {
    const int ec = blockIdx.x, h = blockIdx.y, mat = blockIdx.z;
    const float* W = (mat == 0) ? Wq : ((mat == 1) ? Wk : Wv);
    const int tid = threadIdx.x;
    const int d = tid & 63, es = tid >> 6;
    __shared__ float xs[B_][128];
    __shared__ float red[4][B_][64];
    for (int i = tid; i < B_ * 128; i += 256) {
        int b = i >> 7, e = i & 127;
        xs[b][e] = x[b * DM + ec * 128 + e];
    }
    __syncthreads();
    float acc[B_];
#pragma unroll
    for (int b = 0; b < B_; b++) acc[b] = 0.f;
    for (int i = 0; i < 32; i++) {
        int el = es * 32 + i;
        int e = ec * 128 + el;
        float w = W[((size_t)e * H_ + h) * DH + d];
#pragma unroll
        for (int b = 0; b < B_; b++) acc[b] += xs[b][el] * w;
    }
#pragma unroll
    for (int b = 0; b < B_; b++) red[es][b][d] = acc[b];
    __syncthreads();
    const int b4 = tid >> 6;
#pragma unroll
    for (int bb = 0; bb < 4; bb++) {
        int b = b4 * 4 + bb;
        float v = red[0][b][d] + red[1][b][d] + red[2][b][d] + red[3][b][d];
        ws[WS_BIG + (((size_t)(mat * 8 + ec) * B_ + b) * H_ + h) * DH + d] = v;
    }
}

// 256 blocks (b*h) x 64 threads
__global__ void k_qkvred(float* __restrict__ cached_key, float* __restrict__ cached_value,
                         const float* __restrict__ bq, const float* __restrict__ bk,
                         const float* __restrict__ bv, const int* __restrict__ cidx,
                         float* __restrict__ ws) {
    const int bh = blockIdx.x, d = threadIdx.x;
    const int b = bh >> 4, h = bh & 15;
    const int P = *cidx;
    float q = bq[h * 64 + d], k = bk[h * 64 + d], v = bv[h * 64 + d];
    const float* big = ws + WS_BIG;
    const size_t matstride = (size_t)8 * B_ * H_ * DH;
#pragma unroll
    for (int ec = 0; ec < 8; ec++) {
        size_t base = (((size_t)ec * B_ + b) * H_ + h) * DH + d;
        q += big[base];
        k += big[matstride + base];
        v += big[2 * matstride + base];
    }
    ws[WS_Q + bh * 64 + d] = q;
    size_t off = (((size_t)b * TMAX + P) * H_ + h) * DH + d;
    cached_key[off] = k;
    cached_value[off] = v;
}

// grid (SPLIT, H, B) = 2048 blocks, block 256
__global__ __launch_bounds__(256) void k_attn(const float* __restrict__ K,
                                              const float* __restrict__ V,
                                              const int* __restrict__ cidx,
                                              float* __restrict__ ws) {
    const int s = blockIdx.x, h = blockIdx.y, b = blockIdx.z;
    const int tid = threadIdx.x;
    const int P = *cidx;
    const int n = P + 1;
    const int chunk = (n + SPLIT - 1) / SPLIT;
    const int t0 = s * chunk;
    int t1 = t0 + chunk; if (t1 > n) t1 = n;
    const int len = (t1 > t0) ? (t1 - t0) : 0;
    const int bh = b * H_ + h;

    __shared__ float qr[64];
    __shared__ float sc[512];
    __shared__ float rb_m[4], rb_s[4];
    __shared__ float ov[16][64];

    if (tid < 64) {
        int d = tid;
        const float* qv = ws + WS_Q + bh * 64;
        int j = (d < 32) ? d : (d - 32);
        float invf = __expf(-(float)j * ROPE_L);
        float sn, c;
        sincosf((float)P * invf, &sn, &c);
        qr[d] = (d < 32) ? (qv[d] * c - qv[d + 32] * sn)
                         : (qv[d - 32] * sn + qv[d] * c);
    }
    __syncthreads();

    // Phase A: 8 lanes per position, fully-coalesced K rows
    const int pos_sub = tid >> 3, q = tid & 7;
    float qa0 = qr[4 * q + 0], qa1 = qr[4 * q + 1], qa2 = qr[4 * q + 2], qa3 = qr[4 * q + 3];
    float qb0 = qr[4 * q + 32], qb1 = qr[4 * q + 33], qb2 = qr[4 * q + 34], qb3 = qr[4 * q + 35];
    float if0 = __expf(-(float)(4 * q + 0) * ROPE_L);
    float if1 = __expf(-(float)(4 * q + 1) * ROPE_L);
    float if2 = __expf(-(float)(4 * q + 2) * ROPE_L);
    float if3 = __expf(-(float)(4 * q + 3) * ROPE_L);

    float tmax = -3.0e38f;
    for (int base = 0; base < len; base += 32) {
        int idx = base + pos_sub;
        bool act = idx < len;
        int t = t0 + idx;
        f4 k1 = {0.f, 0.f, 0.f, 0.f}, k2 = {0.f, 0.f, 0.f, 0.f};
        if (act) {
            const f4* kp = (const f4*)(K + (((size_t)b * TMAX + t) * H_ + h) * DH);
            k1 = ldnt(kp + q);
            k2 = ldnt(kp + q + 8);
        }
        float tf = (float)t;
        float s0, c0, s1, c1, s2, c2, s3, c3;
        sincosf(tf * if0, &s0, &c0);
        sincosf(tf * if1, &s1, &c1);
        sincosf(tf * if2, &s2, &c2);
        sincosf(tf * if3, &s3, &c3);
        float p = k1.x * (qa0 * c0 + qb0 * s0) + k2.x * (qb0 * c0 - qa0 * s0)
                + k1.y * (qa1 * c1 + qb1 * s1) + k2.y * (qb1 * c1 - qa1 * s1)
                + k1.z * (qa2 * c2 + qb2 * s2) + k2.z * (qb2 * c2 - qa2 * s2)
                + k1.w * (qa3 * c3 + qb3 * s3) + k2.w * (qb3 * c3 - qa3 * s3);
#pragma unroll
        for (int o = 1; o < 8; o <<= 1) p += __shfl_xor(p, o, 64);
        if (act) {
            float sv = p * SCALE;
            if (q == 0) sc[idx] = sv;
            tmax = fmaxf(tmax, sv);
        }
    }
    float wm = wred_max(tmax);
    if ((tid & 63) == 0) rb_m[tid >> 6] = wm;
    __syncthreads();
    float m = fmaxf(fmaxf(rb_m[0], rb_m[1]), fmaxf(rb_m[2], rb_m[3]));

    float tsum = 0.f;
    for (int idx = tid; idx < len; idx += 256) {
        float pp = __expf(sc[idx] - m);
        sc[idx] = pp;
        tsum += pp;
    }
    float wsum = wred_sum(tsum);
    if ((tid & 63) == 0) rb_s[tid >> 6] = wsum;
    __syncthreads();
    float l = rb_s[0] + rb_s[1] + rb_s[2] + rb_s[3];

    // Phase B: float4 over d, 16 position-groups, coalesced rows
    const int d4 = tid & 15, grp = tid >> 4;
    f4 acc4 = {0.f, 0.f, 0.f, 0.f};
#pragma unroll 4
    for (int idx = grp; idx < len; idx += 16) {
        int t = t0 + idx;
        const f4* vp = (const f4*)(V + (((size_t)b * TMAX + t) * H_ + h) * DH) + d4;
        f4 vv = ldnt(vp);
        acc4 += sc[idx] * vv;
    }
    *(f4*)&ov[grp][d4 * 4] = acc4;
    __syncthreads();
    if (tid < 64) {
        float o = 0.f;
#pragma unroll
        for (int g = 0; g < 16; g++) o += ov[g][tid];
        ws[WS_PO + ((size_t)bh * SPLIT + s) * 64 + tid] = o;
        if (tid == 0) {
            ws[WS_PM + bh * SPLIT + s] = (len > 0) ? m : -1.0e30f;
            ws[WS_PL + bh * SPLIT + s] = l;
        }
    }
}

// 256 blocks x 64 threads; also seeds out[] with the bias (16K threads == out size)
__global__ void k_combine(const float* __restrict__ bo, float* __restrict__ ws,
                          float* __restrict__ out) {
    int bh = blockIdx.x;
    int d = threadIdx.x;
    const float* pm = ws + WS_PM + bh * SPLIT;
    const float* pl = ws + WS_PL + bh * SPLIT;
    const float* po = ws + WS_PO + (size_t)bh * SPLIT * 64;
    float m = -3.0e38f;
#pragma unroll
    for (int s = 0; s < SPLIT; s++) m = fmaxf(m, pm[s]);
    float l = 0.f, o = 0.f;
#pragma unroll
    for (int s = 0; s < SPLIT; s++) {
        float w = __expf(pm[s] - m);
        l += pl[s] * w;
        o += po[s * 64 + d] * w;
    }
    ws[WS_OF + bh * 64 + d] = o / l;
    int idx = bh * 64 + d;            // 0 .. B_*DM-1
    out[idx] = bo[idx & (DM - 1)];
}

// grid (16 echunks, 16 hdchunks), block 256; accumulates into out via atomics
__global__ __launch_bounds__(256) void k_oproj(const float* __restrict__ Wo,
                        float* __restrict__ ws, float* __restrict__ out) {
    const int ec = blockIdx.x, hc = blockIdx.y;
    const int tid = threadIdx.x;
    const int el = tid & 63, grp = tid >> 6;
    const int e = ec * 64 + el;
    __shared__ float ofs[B_][64];
    __shared__ float red[4][B_][64];
    for (int i = tid; i < B_ * 64; i += 256) {
        int b = i >> 6, j = i & 63;
        ofs[b][j] = ws[WS_OF + b * (H_ * DH) + hc * 64 + j];
    }
    __syncthreads();
    float acc[B_];
#pragma unroll
    for (int b = 0; b < B_; b++) acc[b] = 0.f;
    for (int i = 0; i < 16; i++) {
        int hl = grp * 16 + i;
        int hd = hc * 64 + hl;
        float w = Wo[(size_t)hd * DM + e];
#pragma unroll
        for (int b = 0; b < B_; b++) acc[b] += ofs[b][hl] * w;
    }
#pragma unroll
    for (int b = 0; b < B_; b++) red[grp][b][el] = acc[b];
    __syncthreads();
    const int b4 = tid >> 6;
#pragma unroll
    for (int bb = 0; bb < 4; bb++) {
        int b = b4 * 4 + bb;
        float v = red[0][b][el] + red[1][b][el] + red[2][b][el] + red[3][b][el];
        atomicAdd(&out[(size_t)b * DM + e], v);
    }
}

extern "C" void kernel_launch(void* const* d_in, const int* in_sizes, int n_in,
                              void* d_out, int out_size, void* d_ws, size_t ws_size,
                              hipStream_t stream) {
    const float* x  = (const float*)d_in[0];
    float* ck       = (float*)d_in[1];
    float* cv       = (float*)d_in[2];
    const float* Wq = (const float*)d_in[3];
    const float* bq = (const float*)d_in[4];
    const float* Wk = (const float*)d_in[5];
    const float* bk = (const float*)d_in[6];
    const float* Wv = (const float*)d_in[7];
    const float* bv = (const float*)d_in[8];
    const float* Wo = (const float*)d_in[9];
    const float* bo = (const float*)d_in[10];
    const int* cidx = (const int*)d_in[11];
    float* ws  = (float*)d_ws;
    float* out = (float*)d_out;

    k_qkv<<<dim3(8, H_, 3), 256, 0, stream>>>(x, Wq, Wk, Wv, ws);
    k_qkvred<<<B_ * H_, 64, 0, stream>>>(ck, cv, bq, bk, bv, cidx, ws);
    k_attn<<<dim3(SPLIT, H_, B_), 256, 0, stream>>>(ck, cv, cidx, ws);
    k_combine<<<B_ * H_, 64, 0, stream>>>(bo, ws, out);
    k_oproj<<<dim3(16, 16), 256, 0, stream>>>(Wo, ws, out);
}